// Round 1
// 244.822 us; speedup vs baseline: 1.0133x; 1.0133x over previous
//
#include <hip/hip_runtime.h>

// ---------------------------------------------------------------------------
// self_transformer: q=xW1^T+b1, k=xW2^T+b2, v=xW3^T+b3,
//                   attn=softmax((k q^T)/sqrt(D)), out=attn@v
// N=4096, D=1024. All matmuls via mfma_f32_16x16x32_bf16, fp32 accum.
// R8 = R7 with the three big GEMMs moved from the 2-barrier 128-tile
//      structure (~520 TF, vmcnt(0) drain right after load issue) to a
//      256x256 / BK=64 / 8-wave deep-pipelined structure:
//      - 2x double-buffered LDS (128 KiB), same zero-conflict XOR-granule
//        swizzle + pre-swizzled global_load_lds sources as R7,
//      - next K-tile staged at the HEAD of the current tile (targets the
//        buffer whose reads drained at the previous tile-boundary barrier
//        -> WAR-safe), waited with vmcnt(0) only AFTER 4 MFMA phases,
//      - raw s_barrier (no __syncthreads vmcnt-drain), setprio(1) around
//        each 16-MFMA quadrant phase.
//      Accumulation order over k identical to R7 -> identical numerics.
// ---------------------------------------------------------------------------

typedef short bf16x8 __attribute__((ext_vector_type(8)));  // 8 bf16 = 4 VGPRs
typedef float f32x4  __attribute__((ext_vector_type(4)));

__device__ __forceinline__ short f2bf(float f) {
    unsigned u = __builtin_bit_cast(unsigned, f);
    u += 0x7FFFu + ((u >> 16) & 1u);   // round-to-nearest-even
    return (short)(u >> 16);
}
__device__ __forceinline__ float bf2f(short s) {
    return __builtin_bit_cast(float, (unsigned)((unsigned short)s) << 16);
}

__device__ __forceinline__ void gld_lds16(const short* g, short* l) {
    __builtin_amdgcn_global_load_lds(
        (const __attribute__((address_space(1))) void*)g,
        (__attribute__((address_space(3))) void*)l, 16, 0, 0);
}

// ---------------------------------------------------------------------------
// 256x256 BT GEMM, BK=64, 512 threads = 8 waves (2M x 4N), per-wave 128x64.
// C[a][b] = scale * sum_i A[a*lda+i] * B[b*ldb+i]  (+ per-col bias, CMODE 0)
// CMODE: 0 = bf16 store + bias; 2 = bf16 exp() store; 3 = bf16 store at
//        split-K offset z*zstride (A/B k-offset z*K).
// LDS: XOR-swizzled 16B granules: LDS granule p of row r holds global
// granule p^(r&7); fragment read granule (ks*4+quad)^(r&7) -> conflict-free
// (verified: SQ_LDS_BANK_CONFLICT == 0 with this exact scheme in R7).
// Pipeline per K-tile t: [stage t+1 -> buf^1] [4 quadrant phases from buf]
// [s_waitcnt vmcnt(0); s_barrier]. Stage writes target the buffer that held
// tile t-1, whose last reads drained before the previous boundary barrier.
// ---------------------------------------------------------------------------
template<int CMODE>
__global__ __launch_bounds__(512)
void gemm256(const short* __restrict__ A, int lda,
             const short* __restrict__ B, int ldb,
             const float* __restrict__ bias,
             short* __restrict__ Cout, int ldc, float scale,
             int K, size_t zstride)
{
    __shared__ __align__(16) short As[2][256 * 64];
    __shared__ __align__(16) short Bs[2][256 * 64];

    const int tid  = threadIdx.x;
    const int lane = tid & 63;
    const int wave = tid >> 6;           // 0..7
    const int wr   = wave >> 2;          // 0..1  (M strip of 128 rows)
    const int wc   = wave & 3;           // 0..3  (N strip of 64 cols)
    const int quad = lane >> 4;
    const int l16  = lane & 15;
    const size_t bm0 = (size_t)blockIdx.y * 256;
    const size_t bn0 = (size_t)blockIdx.x * 256;
    const int koff = blockIdx.z * K;

    f32x4 acc[8][4] = {};

    // staging lane decode: chunk row + swizzled global granule
    const int srow = lane >> 3;                        // 0..7
    const int scol = ((lane & 7) ^ srow) << 3;         // swizzled elem col
    const short* Ag = A + (bm0 + srow) * (size_t)lda + koff + scol;
    const short* Bg = B + (bn0 + srow) * (size_t)ldb + koff + scol;

    const int NT = K >> 6;

    // stage one 256x64 K-tile pair (A+B) into buffer b: 8 gld_lds / thread.
    // wave-load j (=wave*4+i) covers rows 8j..8j+7; lane l -> row 8j+(l>>3),
    // LDS granule (l&7), fetching global granule (l&7)^(l>>3).
    auto stage = [&](int b, int k0) {
#pragma unroll
        for (int i = 0; i < 4; ++i) {
            const int j = wave * 4 + i;
            gld_lds16(Ag + (size_t)(8 * j) * lda + k0, &As[b][j * 512]);
        }
#pragma unroll
        for (int i = 0; i < 4; ++i) {
            const int j = wave * 4 + i;
            gld_lds16(Bg + (size_t)(8 * j) * ldb + k0, &Bs[b][j * 512]);
        }
    };

    // prologue: tile 0 -> buf 0
    stage(0, 0);
    asm volatile("s_waitcnt vmcnt(0)" ::: "memory");
    __builtin_amdgcn_s_barrier();
    __builtin_amdgcn_sched_barrier(0);

    bf16x8 af[4][2], bfr[2][2];
    int buf = 0;

    for (int t = 0; t < NT; ++t) {
        // issue next tile's stages first: they land in buf^1 (tile t-1's
        // slot, fully consumed before the barrier we just passed).
        if (t + 1 < NT) stage(buf ^ 1, (t + 1) << 6);

        // 4 phases over C quadrants, order (Mq,Nq) = (0,0),(0,1),(1,1),(1,0)
        // so each transition reloads only the changed half (A:16, B:12
        // ds_read_b128 per tile per wave).
#pragma unroll
        for (int ph = 0; ph < 4; ++ph) {
            const int Mq = ph >> 1;                       // 0,0,1,1
            const int Nq = (ph == 1 || ph == 2) ? 1 : 0;  // 0,1,1,0
            if (ph == 0 || ph == 2) {                     // (re)load A half
#pragma unroll
                for (int m4 = 0; m4 < 4; ++m4) {
                    const int r = wr * 128 + (Mq * 4 + m4) * 16 + l16;
                    const short* base = &As[buf][r * 64];
#pragma unroll
                    for (int ks = 0; ks < 2; ++ks)
                        af[m4][ks] = *(const bf16x8*)(
                            base + ((((ks << 2) + quad) ^ (r & 7)) << 3));
                }
            }
            if (ph != 2) {                                // (re)load B half
#pragma unroll
                for (int n2 = 0; n2 < 2; ++n2) {
                    const int r = wc * 64 + (Nq * 2 + n2) * 16 + l16;
                    const short* base = &Bs[buf][r * 64];
#pragma unroll
                    for (int ks = 0; ks < 2; ++ks)
                        bfr[n2][ks] = *(const bf16x8*)(
                            base + ((((ks << 2) + quad) ^ (r & 7)) << 3));
                }
            }
            __builtin_amdgcn_s_barrier();
            __builtin_amdgcn_s_setprio(1);
#pragma unroll
            for (int ks = 0; ks < 2; ++ks)
#pragma unroll
                for (int m4 = 0; m4 < 4; ++m4)
#pragma unroll
                    for (int n2 = 0; n2 < 2; ++n2)
                        acc[Mq * 4 + m4][Nq * 2 + n2] =
                            __builtin_amdgcn_mfma_f32_16x16x32_bf16(
                                af[m4][ks], bfr[n2][ks],
                                acc[Mq * 4 + m4][Nq * 2 + n2], 0, 0, 0);
            __builtin_amdgcn_s_setprio(0);
            __builtin_amdgcn_s_barrier();
        }

        // tile boundary: my stages for tile t+1 have had 4 phases of MFMA
        // to land; drain the residue, then publish to all waves.
        asm volatile("s_waitcnt vmcnt(0)" ::: "memory");
        __builtin_amdgcn_s_barrier();
        __builtin_amdgcn_sched_barrier(0);
        buf ^= 1;
    }

    // epilogue: C/D layout col=lane&15, row=quad*4+reg
    short* Cs = Cout + ((CMODE == 3) ? (size_t)blockIdx.z * zstride : 0);
#pragma unroll
    for (int mt = 0; mt < 8; ++mt) {
#pragma unroll
        for (int nt = 0; nt < 4; ++nt) {
            const size_t col = bn0 + wc * 64 + nt * 16 + l16;
            const float bc = (CMODE == 0) ? bias[col] : 0.0f;
#pragma unroll
            for (int r = 0; r < 4; ++r) {
                const size_t row = bm0 + wr * 128 + mt * 16 + quad * 4 + r;
                float v = acc[mt][nt][r] * scale + bc;
                if (CMODE == 2) v = __expf(v);
                Cs[row * (size_t)ldc + col] = f2bf(v);
            }
        }
    }
}

// 64x64 LDS-tiled transpose: vt[d][n] = qkv[n*3072 + 2048 + d]
__global__ __launch_bounds__(256)
void transpose_v(const short* __restrict__ qkv, short* __restrict__ vt)
{
    __shared__ short sh[64][72];   // +8 pad
    const int n0 = blockIdx.x * 64, d0 = blockIdx.y * 64;
    const int t = threadIdx.x;
    const int r = t >> 2, c = (t & 3) << 4;

    const short* src = qkv + (size_t)(n0 + r) * 3072 + 2048 + d0 + c;
    *(int4*)(&sh[r][c])     = *(const int4*)(src);
    *(int4*)(&sh[r][c + 8]) = *(const int4*)(src + 8);
    __syncthreads();

    short tmp[16];
#pragma unroll
    for (int j = 0; j < 16; j++) tmp[j] = sh[c + j][r];
    short* dst = vt + (size_t)(d0 + r) * 4096 + n0 + c;
    *(int4*)(dst)     = *(const int4*)(tmp);
    *(int4*)(dst + 8) = *(const int4*)(tmp + 8);
}

// One block per output row n: rsum = sum(E[n,:]); out[n,:] =
// (sum_z partial_z[n,:]) / rsum. Partials are bf16, 4 splits of 4096x1024.
__global__ __launch_bounds__(256)
void reduce4div(const short* __restrict__ E, const short* __restrict__ outp,
                float* __restrict__ out)
{
    const int row = blockIdx.x;
    const int t = threadIdx.x;
    const int wave = t >> 6, lane = t & 63;

    // row-sum of E[row][4096], 16 elems/thread
    const short* e = E + (size_t)row * 4096 + (t << 4);
    short sh[16];
    *(int4*)(sh)     = *(const int4*)(e);
    *(int4*)(sh + 8) = *(const int4*)(e + 8);
    float s = 0.0f;
#pragma unroll
    for (int i = 0; i < 16; i++) s += bf2f(sh[i]);
#pragma unroll
    for (int off = 32; off; off >>= 1) s += __shfl_down(s, off);
    __shared__ float red[4];
    if (lane == 0) red[wave] = s;
    __syncthreads();
    const float inv = 1.0f / (red[0] + red[1] + red[2] + red[3]);

    // sum 4 bf16 partial rows, 4 cols/thread
    const size_t base = (size_t)row * 1024 + (t << 2);
    float a[4] = {0.0f, 0.0f, 0.0f, 0.0f};
#pragma unroll
    for (int z = 0; z < 4; z++) {
        short4 p = *(const short4*)(outp + z * (size_t)4096 * 1024 + base);
        a[0] += bf2f(p.x); a[1] += bf2f(p.y);
        a[2] += bf2f(p.z); a[3] += bf2f(p.w);
    }
    float4 o;
    o.x = a[0] * inv; o.y = a[1] * inv; o.z = a[2] * inv; o.w = a[3] * inv;
    *(float4*)(out + base) = o;
}

// single prep: x->xb (1M float4), W1|W2|W3 -> Wb (3x256K float4), bias cat
// Wb sub-matrix offsets are in SHORT ELEMENTS (1048576 elems per W).
__global__ __launch_bounds__(256)
void prep(const float* __restrict__ x, const float* __restrict__ W1,
          const float* __restrict__ W2, const float* __restrict__ W3,
          const float* __restrict__ b1, const float* __restrict__ b2,
          const float* __restrict__ b3,
          short* __restrict__ xb, short* __restrict__ Wb,
          float* __restrict__ bcat)
{
    const int i = blockIdx.x * 256 + threadIdx.x;
    const int NX = 1048576;           // 4096*1024/4
    const int NW = 262144;            // 1024*1024/4
    if (i < NX + 3 * NW) {
        const float* src; short* dst; int j;
        if (i < NX)               { src = x;  dst = xb; j = i; }
        else if (i < NX + NW)     { src = W1; dst = Wb; j = i - NX; }
        else if (i < NX + 2 * NW) { src = W2; dst = Wb + 1048576; j = i - NX - NW; }
        else                      { src = W3; dst = Wb + 2097152; j = i - NX - 2 * NW; }
        const float4 f = ((const float4*)src)[j];
        short4 o;
        o.x = f2bf(f.x); o.y = f2bf(f.y); o.z = f2bf(f.z); o.w = f2bf(f.w);
        *(short4*)(dst + (j << 2)) = o;
    } else {
        const int j = i - (NX + 3 * NW);
        if (j < 3072)
            bcat[j] = (j < 1024) ? b1[j] : (j < 2048 ? b2[j - 1024] : b3[j - 2048]);
    }
}

extern "C" void kernel_launch(void* const* d_in, const int* in_sizes, int n_in,
                              void* d_out, int out_size, void* d_ws, size_t ws_size,
                              hipStream_t stream)
{
    const float* x  = (const float*)d_in[0];
    const float* W1 = (const float*)d_in[1];
    const float* b1 = (const float*)d_in[2];
    const float* W2 = (const float*)d_in[3];
    const float* b2 = (const float*)d_in[4];
    const float* W3 = (const float*)d_in[5];
    const float* b3 = (const float*)d_in[6];
    float* out = (float*)d_out;

    const int N = 4096, D = 1024;

    // workspace (peak 79 MB):
    //   vt   [0, 8M)            live: transpose .. out-gemm
    //   E    [8M, 40M)          live: S-gemm .. reduce
    //   xb   [40M, 48M)  \
    //   Wb   [48M, 54M)   }     dead after S-gemm
    //   bcat [54M, +12K)  }
    //   qkv  [54M+16K, ~78M)   /
    //   outp [40M, 72M)         bf16 partials, overlays dead region
    char* wsb = (char*)d_ws;
    short* vt   = (short*)wsb;                               // 1024x4096 bf16
    short* E    = (short*)(wsb + (size_t)8  * 1024 * 1024);  // 4096x4096 bf16
    short* xb   = (short*)(wsb + (size_t)40 * 1024 * 1024);  // 4096x1024 bf16
    short* Wb   = (short*)(wsb + (size_t)48 * 1024 * 1024);  // 3072x1024 bf16
    float* bcat = (float*)(wsb + (size_t)54 * 1024 * 1024);  // 3072 fp32
    short* qkv  = (short*)(wsb + (size_t)54 * 1024 * 1024 + 16384); // 4096x3072
    short* outp = (short*)(wsb + (size_t)40 * 1024 * 1024);  // 4x 4096x1024 bf16

    // 1) prep: casts + bias concat (one launch)
    prep<<<(1048576 + 3 * 262144 + 3072 + 255) / 256, 256, 0, stream>>>(
        x, W1, W2, W3, b1, b2, b3, xb, Wb, bcat);

    // 2) qkv = x @ [W1;W2;W3]^T + bias  (256x256, grid (12,16)=192)
    dim3 gqkv(3 * D / 256, N / 256);
    gemm256<0><<<gqkv, 512, 0, stream>>>(xb, D, Wb, D, bcat,
                                         qkv, 3 * D, 1.0f, D, 0);

    // 3) vt[d][n] = v[n][d]   grid (64,16)=1024 blocks
    dim3 gt(N / 64, D / 64);
    transpose_v<<<gt, 256, 0, stream>>>(qkv, vt);

    // 4) E = exp((k q^T)/32) bf16  (256x256, grid (16,16)=256)
    dim3 gs(N / 256, N / 256);
    gemm256<2><<<gs, 512, 0, stream>>>(qkv + D, 3 * D, qkv, 3 * D,
                                       nullptr, E, N, 0.03125f, D, 0);

    // 5) out partials = E @ vt^T, split-K=4, bf16 (grid (4,16,4)=256)
    dim3 go(D / 256, N / 256, 4);
    gemm256<3><<<go, 512, 0, stream>>>(E, N, vt, N, nullptr,
                                       outp, D, 1.0f, N / 4,
                                       (size_t)N * D);

    // 6) out = (sum_z partial_z) / rowsum(E)
    reduce4div<<<N, 256, 0, stream>>>(E, outp, out);
}

// Round 2
// 220.588 us; speedup vs baseline: 1.1246x; 1.1099x over previous
//
#include <hip/hip_runtime.h>

// ---------------------------------------------------------------------------
// self_transformer: q=xW1^T+b1, k=xW2^T+b2, v=xW3^T+b3,
//                   attn=softmax((k q^T)/sqrt(D)), out=attn@v
// N=4096, D=1024. All matmuls via mfma_f32_16x16x32_bf16, fp32 accum.
// R9 = R8 with the true counted-vmcnt pipeline (T3+T4): each BK=64 tile is
//      split into two k-halves; phases are (ks, m-half) so the first two
//      phases of a tile touch only kh0 -> kh1 can stay IN FLIGHT across the
//      tile boundary. vmcnt(4) (never 0) at mid-tile and boundary, one
//      2-load stage per phase (continuous HBM demand). LDS layout
//      [buf][kh][256 rows][32 cols] with slot = granule ^ ((row>>1)&3)
//      swizzle (2 touches/bank per 16-lane quarter on ds_read_b128, linear
//      gld_lds destinations). Accumulation order ks0->ks1 per tile is
//      unchanged -> bit-identical numerics to R8.
// ---------------------------------------------------------------------------

typedef short bf16x8 __attribute__((ext_vector_type(8)));  // 8 bf16 = 4 VGPRs
typedef float f32x4  __attribute__((ext_vector_type(4)));

__device__ __forceinline__ short f2bf(float f) {
    unsigned u = __builtin_bit_cast(unsigned, f);
    u += 0x7FFFu + ((u >> 16) & 1u);   // round-to-nearest-even
    return (short)(u >> 16);
}
__device__ __forceinline__ float bf2f(short s) {
    return __builtin_bit_cast(float, (unsigned)((unsigned short)s) << 16);
}

__device__ __forceinline__ void gld_lds16(const short* g, short* l) {
    __builtin_amdgcn_global_load_lds(
        (const __attribute__((address_space(1))) void*)g,
        (__attribute__((address_space(3))) void*)l, 16, 0, 0);
}

// counted waitcnt with compiler memory fence: blocks ds_read/gld_lds motion
// across it, so issue-order windows (kh0 before kh1) are preserved.
#define WAITV(n) asm volatile("s_waitcnt vmcnt(" #n ")" ::: "memory")

// ---------------------------------------------------------------------------
// 256x256 BT GEMM, BK=64 (2 k-halves of 32), 512 threads = 8 waves (2M x 4N),
// per-wave 128x64 output. C[a][b] = scale * sum_i A[a*lda+i] * B[b*ldb+i]
// CMODE: 0 = bf16 store + bias; 2 = bf16 exp() store; 3 = bf16 store at
//        split-K offset z*zstride (A/B k-offset z*K).
//
// Steady state per tile t (buf = cur, buf^1 = nxt):
//   entering: kh0(t) landed+published, kh1(t) in flight (4 loads/wave)
//   ph1: ds_read A[ks0,m0-3]+B[ks0]  | stage A-kh0(t+1) | bar | 16 MFMA | bar
//   ph2: ds_read A[ks0,m4-7]         | stage B-kh0(t+1) | bar | 16 MFMA
//        WAITV(4) -> kh1(t) landed; bar (collective)
//   ph3: ds_read A[ks1,m0-3]+B[ks1]  | stage A-kh1(t+1) | bar | 16 MFMA | bar
//   ph4: ds_read A[ks1,m4-7]         | stage B-kh1(t+1) | bar | 16 MFMA
//        WAITV(4) -> kh0(t+1) landed; bar  -> buf ^= 1
// vmcnt is per-wave; the barrier AFTER each WAITV makes completion collective.
// ---------------------------------------------------------------------------
template<int CMODE>
__global__ __launch_bounds__(512)
void gemm256(const short* __restrict__ A, int lda,
             const short* __restrict__ B, int ldb,
             const float* __restrict__ bias,
             short* __restrict__ Cout, int ldc, float scale,
             int K, size_t zstride)
{
    __shared__ __align__(16) short As[2][2][256 * 32];
    __shared__ __align__(16) short Bs[2][2][256 * 32];

    const int tid  = threadIdx.x;
    const int lane = tid & 63;
    const int wave = tid >> 6;           // 0..7
    const int wr   = wave >> 2;          // 0..1  (M strip of 128 rows)
    const int wc   = wave & 3;           // 0..3  (N strip of 64 cols)
    const int quad = lane >> 4;
    const int l16  = lane & 15;
    const size_t bm0 = (size_t)blockIdx.y * 256;
    const size_t bn0 = (size_t)blockIdx.x * 256;
    const int koff = blockIdx.z * K;

    f32x4 acc[8][4] = {};

    // staging decode: load j covers rows j*16..j*16+15 of one k-half.
    // lane l -> row j*16+(l>>2), LDS slot (l&3), global granule
    // (l&3)^((l>>3)&3)   [ (row>>1)&3 == (l>>3)&3 since j*16/2 % 4 == 0 ]
    const int srow  = lane >> 2;
    const int sgran = (lane & 3) ^ ((lane >> 3) & 3);
    const short* Ag = A + (bm0 + srow) * (size_t)lda + koff + sgran * 8;
    const short* Bg = B + (bn0 + srow) * (size_t)ldb + koff + sgran * 8;

    // frag-read offsets within a [256][32] plane: row r = R0 + l16, want
    // global granule `quad` -> slot = quad ^ ((r>>1)&3) = quad ^ ((l16>>1)&3)
    const int slotr = quad ^ ((l16 >> 1) & 3);
    const int rdA = (wr * 128 + l16) * 32 + slotr * 8;
    const int rdB = (wc * 64  + l16) * 32 + slotr * 8;

    const int NT = K >> 6;

    auto stA = [&](int b, int kh, int k0) {     // 2 loads/thread, 16KB total
#pragma unroll
        for (int i = 0; i < 2; ++i) {
            const int j = wave * 2 + i;
            gld_lds16(Ag + (size_t)(j * 16) * lda + k0 + kh * 32,
                      &As[b][kh][j * 16 * 32]);
        }
    };
    auto stB = [&](int b, int kh, int k0) {
#pragma unroll
        for (int i = 0; i < 2; ++i) {
            const int j = wave * 2 + i;
            gld_lds16(Bg + (size_t)(j * 16) * ldb + k0 + kh * 32,
                      &Bs[b][kh][j * 16 * 32]);
        }
    };

    bf16x8 af[4], bfr[4];

    auto ldA = [&](int b, int ks, int mh) {
        const short* base = &As[b][ks][rdA + mh * 64 * 32];
#pragma unroll
        for (int m4 = 0; m4 < 4; ++m4)
            af[m4] = *(const bf16x8*)(base + m4 * 16 * 32);
    };
    auto ldB = [&](int b, int ks) {
        const short* base = &Bs[b][ks][rdB];
#pragma unroll
        for (int nt = 0; nt < 4; ++nt)
            bfr[nt] = *(const bf16x8*)(base + nt * 16 * 32);
    };
    auto mmac = [&](int mh) {
        __builtin_amdgcn_s_setprio(1);
#pragma unroll
        for (int m4 = 0; m4 < 4; ++m4)
#pragma unroll
            for (int nt = 0; nt < 4; ++nt)
                acc[mh * 4 + m4][nt] = __builtin_amdgcn_mfma_f32_16x16x32_bf16(
                    af[m4], bfr[nt], acc[mh * 4 + m4][nt], 0, 0, 0);
        __builtin_amdgcn_s_setprio(0);
    };

    // prologue: tile 0, issue kh0 then kh1; wait only kh0 (kh1 stays in
    // flight -> steady state from the first tile).
    stA(0, 0, 0); stB(0, 0, 0);
    stA(0, 1, 0); stB(0, 1, 0);
    WAITV(4);
    __builtin_amdgcn_s_barrier();

    int buf = 0;
    for (int t = 0; t < NT; ++t) {
        const int k1 = (t + 1) << 6;
        const bool more = (t + 1) < NT;

        // phase 1: ks=0, mh=0 (+ all B ks0)
        ldA(buf, 0, 0); ldB(buf, 0);
        if (more) stA(buf ^ 1, 0, k1);
        __builtin_amdgcn_s_barrier();
        mmac(0);
        __builtin_amdgcn_s_barrier();

        // phase 2: ks=0, mh=1
        ldA(buf, 0, 1);
        if (more) stB(buf ^ 1, 0, k1);
        __builtin_amdgcn_s_barrier();
        mmac(1);
        // mid wait: kh1(t) landed (oldest 4 of [kh1(t), kh0(t+1)])
        if (more) { WAITV(4); } else { WAITV(0); }
        __builtin_amdgcn_s_barrier();

        // phase 3: ks=1, mh=0 (+ all B ks1)
        ldA(buf, 1, 0); ldB(buf, 1);
        if (more) stA(buf ^ 1, 1, k1);
        __builtin_amdgcn_s_barrier();
        mmac(0);
        __builtin_amdgcn_s_barrier();

        // phase 4: ks=1, mh=1
        ldA(buf, 1, 1);
        if (more) stB(buf ^ 1, 1, k1);
        __builtin_amdgcn_s_barrier();
        mmac(1);
        // boundary wait: kh0(t+1) landed (oldest 4 of 8); kh1(t+1) flies on
        if (more) {
            WAITV(4);
            __builtin_amdgcn_s_barrier();
        }
        buf ^= 1;
    }

    // epilogue: C/D layout col=lane&15, row=quad*4+reg
    short* Cs = Cout + ((CMODE == 3) ? (size_t)blockIdx.z * zstride : 0);
#pragma unroll
    for (int mt = 0; mt < 8; ++mt) {
#pragma unroll
        for (int nt = 0; nt < 4; ++nt) {
            const size_t col = bn0 + wc * 64 + nt * 16 + l16;
            const float bc = (CMODE == 0) ? bias[col] : 0.0f;
#pragma unroll
            for (int r = 0; r < 4; ++r) {
                const size_t row = bm0 + wr * 128 + mt * 16 + quad * 4 + r;
                float v = acc[mt][nt][r] * scale + bc;
                if (CMODE == 2) v = __expf(v);
                Cs[row * (size_t)ldc + col] = f2bf(v);
            }
        }
    }
}

// 64x64 LDS-tiled transpose: vt[d][n] = qkv[n*3072 + 2048 + d]
__global__ __launch_bounds__(256)
void transpose_v(const short* __restrict__ qkv, short* __restrict__ vt)
{
    __shared__ short sh[64][72];   // +8 pad
    const int n0 = blockIdx.x * 64, d0 = blockIdx.y * 64;
    const int t = threadIdx.x;
    const int r = t >> 2, c = (t & 3) << 4;

    const short* src = qkv + (size_t)(n0 + r) * 3072 + 2048 + d0 + c;
    *(int4*)(&sh[r][c])     = *(const int4*)(src);
    *(int4*)(&sh[r][c + 8]) = *(const int4*)(src + 8);
    __syncthreads();

    short tmp[16];
#pragma unroll
    for (int j = 0; j < 16; j++) tmp[j] = sh[c + j][r];
    short* dst = vt + (size_t)(d0 + r) * 4096 + n0 + c;
    *(int4*)(dst)     = *(const int4*)(tmp);
    *(int4*)(dst + 8) = *(const int4*)(tmp + 8);
}

// One block per output row n: rsum = sum(E[n,:]); out[n,:] =
// (sum_z partial_z[n,:]) / rsum. Partials are bf16, 4 splits of 4096x1024.
__global__ __launch_bounds__(256)
void reduce4div(const short* __restrict__ E, const short* __restrict__ outp,
                float* __restrict__ out)
{
    const int row = blockIdx.x;
    const int t = threadIdx.x;
    const int wave = t >> 6, lane = t & 63;

    // row-sum of E[row][4096], 16 elems/thread
    const short* e = E + (size_t)row * 4096 + (t << 4);
    short sh[16];
    *(int4*)(sh)     = *(const int4*)(e);
    *(int4*)(sh + 8) = *(const int4*)(e + 8);
    float s = 0.0f;
#pragma unroll
    for (int i = 0; i < 16; i++) s += bf2f(sh[i]);
#pragma unroll
    for (int off = 32; off; off >>= 1) s += __shfl_down(s, off);
    __shared__ float red[4];
    if (lane == 0) red[wave] = s;
    __syncthreads();
    const float inv = 1.0f / (red[0] + red[1] + red[2] + red[3]);

    // sum 4 bf16 partial rows, 4 cols/thread
    const size_t base = (size_t)row * 1024 + (t << 2);
    float a[4] = {0.0f, 0.0f, 0.0f, 0.0f};
#pragma unroll
    for (int z = 0; z < 4; z++) {
        short4 p = *(const short4*)(outp + z * (size_t)4096 * 1024 + base);
        a[0] += bf2f(p.x); a[1] += bf2f(p.y);
        a[2] += bf2f(p.z); a[3] += bf2f(p.w);
    }
    float4 o;
    o.x = a[0] * inv; o.y = a[1] * inv; o.z = a[2] * inv; o.w = a[3] * inv;
    *(float4*)(out + base) = o;
}

// single prep: x->xb (1M float4), W1|W2|W3 -> Wb (3x256K float4), bias cat
// Wb sub-matrix offsets are in SHORT ELEMENTS (1048576 elems per W).
__global__ __launch_bounds__(256)
void prep(const float* __restrict__ x, const float* __restrict__ W1,
          const float* __restrict__ W2, const float* __restrict__ W3,
          const float* __restrict__ b1, const float* __restrict__ b2,
          const float* __restrict__ b3,
          short* __restrict__ xb, short* __restrict__ Wb,
          float* __restrict__ bcat)
{
    const int i = blockIdx.x * 256 + threadIdx.x;
    const int NX = 1048576;           // 4096*1024/4
    const int NW = 262144;            // 1024*1024/4
    if (i < NX + 3 * NW) {
        const float* src; short* dst; int j;
        if (i < NX)               { src = x;  dst = xb; j = i; }
        else if (i < NX + NW)     { src = W1; dst = Wb; j = i - NX; }
        else if (i < NX + 2 * NW) { src = W2; dst = Wb + 1048576; j = i - NX - NW; }
        else                      { src = W3; dst = Wb + 2097152; j = i - NX - 2 * NW; }
        const float4 f = ((const float4*)src)[j];
        short4 o;
        o.x = f2bf(f.x); o.y = f2bf(f.y); o.z = f2bf(f.z); o.w = f2bf(f.w);
        *(short4*)(dst + (j << 2)) = o;
    } else {
        const int j = i - (NX + 3 * NW);
        if (j < 3072)
            bcat[j] = (j < 1024) ? b1[j] : (j < 2048 ? b2[j - 1024] : b3[j - 2048]);
    }
}

extern "C" void kernel_launch(void* const* d_in, const int* in_sizes, int n_in,
                              void* d_out, int out_size, void* d_ws, size_t ws_size,
                              hipStream_t stream)
{
    const float* x  = (const float*)d_in[0];
    const float* W1 = (const float*)d_in[1];
    const float* b1 = (const float*)d_in[2];
    const float* W2 = (const float*)d_in[3];
    const float* b2 = (const float*)d_in[4];
    const float* W3 = (const float*)d_in[5];
    const float* b3 = (const float*)d_in[6];
    float* out = (float*)d_out;

    const int N = 4096, D = 1024;

    // workspace (peak 79 MB):
    //   vt   [0, 8M)            live: transpose .. out-gemm
    //   E    [8M, 40M)          live: S-gemm .. reduce
    //   xb   [40M, 48M)  \
    //   Wb   [48M, 54M)   }     dead after S-gemm
    //   bcat [54M, +12K)  }
    //   qkv  [54M+16K, ~78M)   /
    //   outp [40M, 72M)         bf16 partials, overlays dead region
    char* wsb = (char*)d_ws;
    short* vt   = (short*)wsb;                               // 1024x4096 bf16
    short* E    = (short*)(wsb + (size_t)8  * 1024 * 1024);  // 4096x4096 bf16
    short* xb   = (short*)(wsb + (size_t)40 * 1024 * 1024);  // 4096x1024 bf16
    short* Wb   = (short*)(wsb + (size_t)48 * 1024 * 1024);  // 3072x1024 bf16
    float* bcat = (float*)(wsb + (size_t)54 * 1024 * 1024);  // 3072 fp32
    short* qkv  = (short*)(wsb + (size_t)54 * 1024 * 1024 + 16384); // 4096x3072
    short* outp = (short*)(wsb + (size_t)40 * 1024 * 1024);  // 4x 4096x1024 bf16

    // 1) prep: casts + bias concat (one launch)
    prep<<<(1048576 + 3 * 262144 + 3072 + 255) / 256, 256, 0, stream>>>(
        x, W1, W2, W3, b1, b2, b3, xb, Wb, bcat);

    // 2) qkv = x @ [W1;W2;W3]^T + bias  (256x256, grid (12,16)=192)
    dim3 gqkv(3 * D / 256, N / 256);
    gemm256<0><<<gqkv, 512, 0, stream>>>(xb, D, Wb, D, bcat,
                                         qkv, 3 * D, 1.0f, D, 0);

    // 3) vt[d][n] = v[n][d]   grid (64,16)=1024 blocks
    dim3 gt(N / 64, D / 64);
    transpose_v<<<gt, 256, 0, stream>>>(qkv, vt);

    // 4) E = exp((k q^T)/32) bf16  (256x256, grid (16,16)=256)
    dim3 gs(N / 256, N / 256);
    gemm256<2><<<gs, 512, 0, stream>>>(qkv + D, 3 * D, qkv, 3 * D,
                                       nullptr, E, N, 0.03125f, D, 0);

    // 5) out partials = E @ vt^T, split-K=4, bf16 (grid (4,16,4)=256)
    dim3 go(D / 256, N / 256, 4);
    gemm256<3><<<go, 512, 0, stream>>>(E, N, vt, N, nullptr,
                                       outp, D, 1.0f, N / 4,
                                       (size_t)N * D);

    // 6) out = (sum_z partial_z) / rowsum(E)
    reduce4div<<<N, 256, 0, stream>>>(E, outp, out);
}

// Round 3
// 219.221 us; speedup vs baseline: 1.1316x; 1.0062x over previous
//
#include <hip/hip_runtime.h>

// ---------------------------------------------------------------------------
// self_transformer: q=xW1^T+b1, k=xW2^T+b2, v=xW3^T+b3,
//                   attn=softmax((k q^T)/sqrt(D)), out=attn@v
// N=4096, D=1024. All matmuls via mfma_f32_16x16x32_bf16, fp32 accum.
// R10 = R9 with the deep 8-phase schedule (m201-form):
//   - iteration = 2 K-tiles (even->parity0 slots, odd->parity1), phase =
//     one C-quadrant x K=64 (16 MFMA);
//   - A-half = M-quadrant (rows mq*128..+127), B-half = N-quadrant ->
//     every LDS half-slot has a COMPILE-TIME address;
//   - quadrant tour (0,0),(0,1),(1,1),(1,0): A frags reload ph0/ph2,
//     B(nq0) loaded ph0 & reused ph3, B(nq1) loaded ph1 & reused ph2
//     -> ds_reads 12/4/8/0 per phase (24/tile);
//   - one half-tile stage (2 gld_lds) per phase, rotated >=2 phases after
//     the slot's last LDS read:
//       ph0: t+1.Ah1->As[1][1] (read prev ph6)   ph4: t+2.Ah1->As[0][1] (ph2)
//       ph1: t+1.Bh0->Bs[1][0] (read prev ph4)   ph5: t+2.Bh0->Bs[0][0] (ph0)
//       ph2: t+2.Ah0->As[0][0] (read ph0)        ph6: t+3.Ah0->As[1][0] (ph4)
//       ph3: t+2.Bh1->Bs[0][1] (read ph1)        ph7: t+3.Bh1->Bs[1][1] (ph5)
//   - sync: ONE s_barrier per phase ph0-ph2/ph4-ph6 (pre-MFMA) + publish
//     WAITV(4)+barrier at end-ph3 / end-ph7 only. vmcnt never drains to 0
//     except the final iteration. Depth = 3..6 phases per load.
//   Publish ledger (steady state): end-ph3 vmcnt(4) leaves {ph2,ph3} stages
//   in flight -> retires t+1.{Ah1,Bh0} (+older) => tile t+1 fully landed
//   before ph4. end-ph7 vmcnt(4) leaves {ph6,ph7} -> retires through ph5 =>
//   tile t+2 fully landed before next-iter ph0.
//   Same XOR-granule swizzle (0 bank conflicts in R7-R9); same per-element
//   k-order (ks0->ks1 per tile) -> bit-identical numerics to R9.
// ---------------------------------------------------------------------------

typedef short bf16x8 __attribute__((ext_vector_type(8)));  // 8 bf16 = 4 VGPRs
typedef float f32x4  __attribute__((ext_vector_type(4)));

__device__ __forceinline__ short f2bf(float f) {
    unsigned u = __builtin_bit_cast(unsigned, f);
    u += 0x7FFFu + ((u >> 16) & 1u);   // round-to-nearest-even
    return (short)(u >> 16);
}
__device__ __forceinline__ float bf2f(short s) {
    return __builtin_bit_cast(float, (unsigned)((unsigned short)s) << 16);
}

__device__ __forceinline__ void gld_lds16(const short* g, short* l) {
    __builtin_amdgcn_global_load_lds(
        (const __attribute__((address_space(1))) void*)g,
        (__attribute__((address_space(3))) void*)l, 16, 0, 0);
}

// counted waitcnt with compiler memory fence: orders ds_read/gld_lds across it
#define WAITV(n) asm volatile("s_waitcnt vmcnt(" #n ")" ::: "memory")
#define BAR() __builtin_amdgcn_s_barrier()

// ---------------------------------------------------------------------------
// 256x256 BT GEMM, BK=64, 512 threads = 8 waves (2M x 4N), per-wave 128x64
// output spread as rows {wr*64..+63} u {128+wr*64..}, cols {wc*32..} u
// {128+wc*32..}. C[a][b] = scale * sum_i A[a*lda+i] * B[b*ldb+i].
// CMODE: 0 = bf16 + bias; 2 = bf16 exp(); 3 = bf16 at split-K z*zstride.
// LDS half [128 rows][8 granules of 8 shorts]: slot s of row r holds global
// granule s^(r&7); read granule ks*4+quad -> slot (ks*4+quad)^(l16&7).
// ---------------------------------------------------------------------------
template<int CMODE>
__global__ __launch_bounds__(512)
void gemm256(const short* __restrict__ A, int lda,
             const short* __restrict__ B, int ldb,
             const float* __restrict__ bias,
             short* __restrict__ Cout, int ldc, float scale,
             int K, size_t zstride)
{
    __shared__ __align__(16) short As[2][2][128 * 64];  // [parity][mq-half]
    __shared__ __align__(16) short Bs[2][2][128 * 64];  // [parity][nq-half]

    const int tid  = threadIdx.x;
    const int lane = tid & 63;
    const int wave = tid >> 6;           // 0..7
    const int wr   = wave >> 2;          // 0..1
    const int wc   = wave & 3;           // 0..3
    const int quad = lane >> 4;
    const int l16  = lane & 15;
    const size_t bm0 = (size_t)blockIdx.y * 256;
    const size_t bn0 = (size_t)blockIdx.x * 256;
    const int koff = blockIdx.z * K;

    f32x4 acc[8][4] = {};

    // staging decode: load (wave,i) covers rows wave*16+i*8 .. +7 of a half.
    // lane l -> row +(l>>3), writes LDS slot (l&7), fetches granule
    // (l&7)^(l>>3)  [row&7 == l>>3 since row base is a multiple of 8]
    const int srow  = lane >> 3;
    const int sgran = (lane & 7) ^ srow;
    const short* Ag0 = A + (bm0 + wave * 16 + srow) * (size_t)lda + koff + sgran * 8;
    const short* Ag1 = Ag0 + (size_t)128 * lda;
    const short* Bg0 = B + (bn0 + wave * 16 + srow) * (size_t)ldb + koff + sgran * 8;
    const short* Bg1 = Bg0 + (size_t)128 * ldb;

    // fragment read offsets (within a [128][64] half)
    const int s0  = ((quad ^ (l16 & 7)) << 3);          // ks=0 slot byte/2
    const int s1  = (((4 + quad) ^ (l16 & 7)) << 3);    // ks=1
    const int rdA0 = (wr * 64 + l16) * 64;
    const int rdB0 = (wc * 32 + l16) * 64;

    const int NT = K >> 6;

    auto stage = [&](short* half, const short* g, int ld, int kt) {
#pragma unroll
        for (int i = 0; i < 2; ++i)
            gld_lds16(g + (size_t)(i * 8) * ld + kt,
                      half + (wave * 16 + i * 8) * 64);
    };

    bf16x8 af[4][2], bfr0[2][2], bfr1[2][2];

    auto ldAf = [&](const short* Ah) {
#pragma unroll
        for (int m4 = 0; m4 < 4; ++m4) {
            af[m4][0] = *(const bf16x8*)(Ah + rdA0 + m4 * 1024 + s0);
            af[m4][1] = *(const bf16x8*)(Ah + rdA0 + m4 * 1024 + s1);
        }
    };
    auto ldBf = [&](bf16x8 (&bx)[2][2], const short* Bh) {
#pragma unroll
        for (int n2 = 0; n2 < 2; ++n2) {
            bx[n2][0] = *(const bf16x8*)(Bh + rdB0 + n2 * 1024 + s0);
            bx[n2][1] = *(const bf16x8*)(Bh + rdB0 + n2 * 1024 + s1);
        }
    };
    auto mm = [&](int mq, int nq, bf16x8 (&bx)[2][2]) {
        __builtin_amdgcn_s_setprio(1);
#pragma unroll
        for (int ks = 0; ks < 2; ++ks)
#pragma unroll
            for (int m4 = 0; m4 < 4; ++m4)
#pragma unroll
                for (int n2 = 0; n2 < 2; ++n2)
                    acc[mq * 4 + m4][nq * 2 + n2] =
                        __builtin_amdgcn_mfma_f32_16x16x32_bf16(
                            af[m4][ks], bx[n2][ks],
                            acc[mq * 4 + m4][nq * 2 + n2], 0, 0, 0);
        __builtin_amdgcn_s_setprio(0);
    };

    // prologue: tile0 (4 halves), then t1.Ah0 + t1.Bh1 (the virtual ph6/ph7
    // stages). vmcnt(4) retires tile0, leaves t1's 4 loads in flight.
    stage(&As[0][0][0], Ag0, lda, 0);
    stage(&As[0][1][0], Ag1, lda, 0);
    stage(&Bs[0][0][0], Bg0, ldb, 0);
    stage(&Bs[0][1][0], Bg1, ldb, 0);
    stage(&As[1][0][0], Ag0, lda, 64);
    stage(&Bs[1][1][0], Bg1, ldb, 64);
    WAITV(4);
    BAR();
    __builtin_amdgcn_sched_barrier(0);

    for (int it = 0; it < NT / 2; ++it) {
        const int k1 = it * 128 + 64;    // tile 2it+1 (always exists)
        const int k2 = it * 128 + 128;   // tile 2it+2
        const int k3 = it * 128 + 192;   // tile 2it+3
        const bool m2 = k2 < K, m3 = k3 < K;

        // ---- tile t (parity 0) ----
        // ph0 (mq0,nq0)
        ldAf(&As[0][0][0]);
        ldBf(bfr0, &Bs[0][0][0]);
        stage(&As[1][1][0], Ag1, lda, k1);
        BAR();
        mm(0, 0, bfr0);
        // ph1 (mq0,nq1)
        ldBf(bfr1, &Bs[0][1][0]);
        stage(&Bs[1][0][0], Bg0, ldb, k1);
        BAR();
        mm(0, 1, bfr1);
        // ph2 (mq1,nq1)
        ldAf(&As[0][1][0]);
        if (m2) stage(&As[0][0][0], Ag0, lda, k2);
        BAR();
        mm(1, 1, bfr1);
        // ph3 (mq1,nq0) — no ds_reads
        if (m2) stage(&Bs[0][1][0], Bg1, ldb, k2);
        mm(1, 0, bfr0);
        if (m2) { WAITV(4); } else { WAITV(0); }   // publish tile t+1
        BAR();

        // ---- tile t+1 (parity 1) ----
        // ph4 (mq0,nq0)
        ldAf(&As[1][0][0]);
        ldBf(bfr0, &Bs[1][0][0]);
        if (m2) stage(&As[0][1][0], Ag1, lda, k2);
        BAR();
        mm(0, 0, bfr0);
        // ph5 (mq0,nq1)
        ldBf(bfr1, &Bs[1][1][0]);
        if (m2) stage(&Bs[0][0][0], Bg0, ldb, k2);
        BAR();
        mm(0, 1, bfr1);
        // ph6 (mq1,nq1)
        ldAf(&As[1][1][0]);
        if (m3) stage(&As[1][0][0], Ag0, lda, k3);
        BAR();
        mm(1, 1, bfr1);
        // ph7 (mq1,nq0) — no ds_reads
        if (m3) stage(&Bs[1][1][0], Bg1, ldb, k3);
        mm(1, 0, bfr0);
        if (m2) {                                   // publish tile t+2
            WAITV(4);
            BAR();
        }
    }

    // epilogue: C/D layout col=lane&15, row=quad*4+reg; wave rows/cols are
    // split across the two quadrant halves.
    short* Cs = Cout + ((CMODE == 3) ? (size_t)blockIdx.z * zstride : 0);
#pragma unroll
    for (int mt = 0; mt < 8; ++mt) {
        const int mq = mt >> 2, m4 = mt & 3;
#pragma unroll
        for (int nt = 0; nt < 4; ++nt) {
            const int nq = nt >> 1, n2 = nt & 1;
            const size_t col = bn0 + nq * 128 + wc * 32 + n2 * 16 + l16;
            const float bc = (CMODE == 0) ? bias[col] : 0.0f;
#pragma unroll
            for (int r = 0; r < 4; ++r) {
                const size_t row = bm0 + mq * 128 + wr * 64 + m4 * 16 + quad * 4 + r;
                float v = acc[mt][nt][r] * scale + bc;
                if (CMODE == 2) v = __expf(v);
                Cs[row * (size_t)ldc + col] = f2bf(v);
            }
        }
    }
}

// 64x64 LDS-tiled transpose: vt[d][n] = qkv[n*3072 + 2048 + d]
__global__ __launch_bounds__(256)
void transpose_v(const short* __restrict__ qkv, short* __restrict__ vt)
{
    __shared__ short sh[64][72];   // +8 pad
    const int n0 = blockIdx.x * 64, d0 = blockIdx.y * 64;
    const int t = threadIdx.x;
    const int r = t >> 2, c = (t & 3) << 4;

    const short* src = qkv + (size_t)(n0 + r) * 3072 + 2048 + d0 + c;
    *(int4*)(&sh[r][c])     = *(const int4*)(src);
    *(int4*)(&sh[r][c + 8]) = *(const int4*)(src + 8);
    __syncthreads();

    short tmp[16];
#pragma unroll
    for (int j = 0; j < 16; j++) tmp[j] = sh[c + j][r];
    short* dst = vt + (size_t)(d0 + r) * 4096 + n0 + c;
    *(int4*)(dst)     = *(const int4*)(tmp);
    *(int4*)(dst + 8) = *(const int4*)(tmp + 8);
}

// One block per output row n: rsum = sum(E[n,:]); out[n,:] =
// (sum_z partial_z[n,:]) / rsum. Partials are bf16, 4 splits of 4096x1024.
__global__ __launch_bounds__(256)
void reduce4div(const short* __restrict__ E, const short* __restrict__ outp,
                float* __restrict__ out)
{
    const int row = blockIdx.x;
    const int t = threadIdx.x;
    const int wave = t >> 6, lane = t & 63;

    // row-sum of E[row][4096], 16 elems/thread
    const short* e = E + (size_t)row * 4096 + (t << 4);
    short sh[16];
    *(int4*)(sh)     = *(const int4*)(e);
    *(int4*)(sh + 8) = *(const int4*)(e + 8);
    float s = 0.0f;
#pragma unroll
    for (int i = 0; i < 16; i++) s += bf2f(sh[i]);
#pragma unroll
    for (int off = 32; off; off >>= 1) s += __shfl_down(s, off);
    __shared__ float red[4];
    if (lane == 0) red[wave] = s;
    __syncthreads();
    const float inv = 1.0f / (red[0] + red[1] + red[2] + red[3]);

    // sum 4 bf16 partial rows, 4 cols/thread
    const size_t base = (size_t)row * 1024 + (t << 2);
    float a[4] = {0.0f, 0.0f, 0.0f, 0.0f};
#pragma unroll
    for (int z = 0; z < 4; z++) {
        short4 p = *(const short4*)(outp + z * (size_t)4096 * 1024 + base);
        a[0] += bf2f(p.x); a[1] += bf2f(p.y);
        a[2] += bf2f(p.z); a[3] += bf2f(p.w);
    }
    float4 o;
    o.x = a[0] * inv; o.y = a[1] * inv; o.z = a[2] * inv; o.w = a[3] * inv;
    *(float4*)(out + base) = o;
}

// single prep: x->xb (1M float4), W1|W2|W3 -> Wb (3x256K float4), bias cat
// Wb sub-matrix offsets are in SHORT ELEMENTS (1048576 elems per W).
__global__ __launch_bounds__(256)
void prep(const float* __restrict__ x, const float* __restrict__ W1,
          const float* __restrict__ W2, const float* __restrict__ W3,
          const float* __restrict__ b1, const float* __restrict__ b2,
          const float* __restrict__ b3,
          short* __restrict__ xb, short* __restrict__ Wb,
          float* __restrict__ bcat)
{
    const int i = blockIdx.x * 256 + threadIdx.x;
    const int NX = 1048576;           // 4096*1024/4
    const int NW = 262144;            // 1024*1024/4
    if (i < NX + 3 * NW) {
        const float* src; short* dst; int j;
        if (i < NX)               { src = x;  dst = xb; j = i; }
        else if (i < NX + NW)     { src = W1; dst = Wb; j = i - NX; }
        else if (i < NX + 2 * NW) { src = W2; dst = Wb + 1048576; j = i - NX - NW; }
        else                      { src = W3; dst = Wb + 2097152; j = i - NX - 2 * NW; }
        const float4 f = ((const float4*)src)[j];
        short4 o;
        o.x = f2bf(f.x); o.y = f2bf(f.y); o.z = f2bf(f.z); o.w = f2bf(f.w);
        *(short4*)(dst + (j << 2)) = o;
    } else {
        const int j = i - (NX + 3 * NW);
        if (j < 3072)
            bcat[j] = (j < 1024) ? b1[j] : (j < 2048 ? b2[j - 1024] : b3[j - 2048]);
    }
}

extern "C" void kernel_launch(void* const* d_in, const int* in_sizes, int n_in,
                              void* d_out, int out_size, void* d_ws, size_t ws_size,
                              hipStream_t stream)
{
    const float* x  = (const float*)d_in[0];
    const float* W1 = (const float*)d_in[1];
    const float* b1 = (const float*)d_in[2];
    const float* W2 = (const float*)d_in[3];
    const float* b2 = (const float*)d_in[4];
    const float* W3 = (const float*)d_in[5];
    const float* b3 = (const float*)d_in[6];
    float* out = (float*)d_out;

    const int N = 4096, D = 1024;

    // workspace (peak 79 MB):
    //   vt   [0, 8M)            live: transpose .. out-gemm
    //   E    [8M, 40M)          live: S-gemm .. reduce
    //   xb   [40M, 48M)  \
    //   Wb   [48M, 54M)   }     dead after S-gemm
    //   bcat [54M, +12K)  }
    //   qkv  [54M+16K, ~78M)   /
    //   outp [40M, 72M)         bf16 partials, overlays dead region
    char* wsb = (char*)d_ws;
    short* vt   = (short*)wsb;                               // 1024x4096 bf16
    short* E    = (short*)(wsb + (size_t)8  * 1024 * 1024);  // 4096x4096 bf16
    short* xb   = (short*)(wsb + (size_t)40 * 1024 * 1024);  // 4096x1024 bf16
    short* Wb   = (short*)(wsb + (size_t)48 * 1024 * 1024);  // 3072x1024 bf16
    float* bcat = (float*)(wsb + (size_t)54 * 1024 * 1024);  // 3072 fp32
    short* qkv  = (short*)(wsb + (size_t)54 * 1024 * 1024 + 16384); // 4096x3072
    short* outp = (short*)(wsb + (size_t)40 * 1024 * 1024);  // 4x 4096x1024 bf16

    // 1) prep: casts + bias concat (one launch)
    prep<<<(1048576 + 3 * 262144 + 3072 + 255) / 256, 256, 0, stream>>>(
        x, W1, W2, W3, b1, b2, b3, xb, Wb, bcat);

    // 2) qkv = x @ [W1;W2;W3]^T + bias  (256x256, grid (12,16)=192)
    dim3 gqkv(3 * D / 256, N / 256);
    gemm256<0><<<gqkv, 512, 0, stream>>>(xb, D, Wb, D, bcat,
                                         qkv, 3 * D, 1.0f, D, 0);

    // 3) vt[d][n] = v[n][d]   grid (64,16)=1024 blocks
    dim3 gt(N / 64, D / 64);
    transpose_v<<<gt, 256, 0, stream>>>(qkv, vt);

    // 4) E = exp((k q^T)/32) bf16  (256x256, grid (16,16)=256)
    dim3 gs(N / 256, N / 256);
    gemm256<2><<<gs, 512, 0, stream>>>(qkv + D, 3 * D, qkv, 3 * D,
                                       nullptr, E, N, 0.03125f, D, 0);

    // 5) out partials = E @ vt^T, split-K=4, bf16 (grid (4,16,4)=256)
    dim3 go(D / 256, N / 256, 4);
    gemm256<3><<<go, 512, 0, stream>>>(E, N, vt, N, nullptr,
                                       outp, D, 1.0f, N / 4,
                                       (size_t)N * D);

    // 6) out = (sum_z partial_z) / rowsum(E)
    reduce4div<<<N, 256, 0, stream>>>(E, outp, out);
}

// Round 4
// 217.969 us; speedup vs baseline: 1.1381x; 1.0057x over previous
//
#include <hip/hip_runtime.h>

// ---------------------------------------------------------------------------
// self_transformer: q=xW1^T+b1, k=xW2^T+b2, v=xW3^T+b3,
//                   attn=softmax((k q^T)/sqrt(D)), out=attn@v
// N=4096, D=1024. All matmuls via mfma_f32_16x16x32_bf16, fp32 accum.
// R11 = R10 with the verbatim m201 8-phase discipline:
//   per phase: {ds_reads, stage 1 half-tile (2 gld_lds), [lgkmcnt(8) if 12
//   reads], s_barrier, lgkmcnt(0)+sched_barrier(0), setprio(1), 16 MFMA,
//   setprio(0), s_barrier}; vmcnt(6) ONLY at ph4/ph8 (3 half-tiles always
//   in flight); last iteration peeled so the hot loop is branch-free and
//   vmcnt(0) appears only there.
//
//   Stage rotation ledger (iteration i handles tiles t=2i [parity0, ph1-4]
//   and t+1 [parity1, ph5-8]; slot = As/Bs[parity][half]):
//     slot  read-ph   staged-at      content        lands-by       margin
//     A11    ph7      ph1 (iter i)   tile t+1 .A1   ph4 vmcnt(6)   3 ph
//     A00    ph1      ph2            tile t+2 .A0   ph8 vmcnt(6)   7 ph
//     B00    ph1      ph3            tile t+2 .B0   ph8 vmcnt(6)   6 ph
//     B01    ph2      ph4            tile t+2 .B1   ph8 vmcnt(6)   6 ph
//     A01    ph3      ph5            tile t+2 .A1   ph8 vmcnt(6)   6 ph
//     A10    ph5      ph6            tile t+3 .A0   next-ph4       7 ph
//     B10    ph5      ph7            tile t+3 .B0   next-ph4       6 ph
//     B11    ph6      ph8            tile t+3 .B1   next-ph4       6 ph
//   WAR safety: each stage lands in a slot whose last ds_read completed
//   >=1 phase earlier (post-MFMA barrier of the read phase makes all
//   waves' reads collectively complete before any wave issues the stage).
//   vmcnt ledger: at ph4-wait, outstanding = {ph2,ph3,ph4}=6 -> retired
//   through ph1 => tile t+1 complete. At ph8-wait, outstanding =
//   {ph6,ph7,ph8}=6 -> retired through ph5 => tile t+2 complete.
//   Accumulation order per element (tile order, ks0->ks1) unchanged ->
//   bit-identical numerics to R10.
// ---------------------------------------------------------------------------

typedef short bf16x8 __attribute__((ext_vector_type(8)));  // 8 bf16 = 4 VGPRs
typedef float f32x4  __attribute__((ext_vector_type(4)));

struct FalseT { static constexpr bool value = false; };
struct TrueT  { static constexpr bool value = true;  };

__device__ __forceinline__ short f2bf(float f) {
    unsigned u = __builtin_bit_cast(unsigned, f);
    u += 0x7FFFu + ((u >> 16) & 1u);   // round-to-nearest-even
    return (short)(u >> 16);
}
__device__ __forceinline__ float bf2f(short s) {
    return __builtin_bit_cast(float, (unsigned)((unsigned short)s) << 16);
}

__device__ __forceinline__ void gld_lds16(const short* g, short* l) {
    __builtin_amdgcn_global_load_lds(
        (const __attribute__((address_space(1))) void*)g,
        (__attribute__((address_space(3))) void*)l, 16, 0, 0);
}

#define WAITV(n) asm volatile("s_waitcnt vmcnt(" #n ")" ::: "memory")
#define LGKM0()  do { asm volatile("s_waitcnt lgkmcnt(0)" ::: "memory"); \
                      __builtin_amdgcn_sched_barrier(0); } while (0)
#define LGKM8()  asm volatile("s_waitcnt lgkmcnt(8)" ::: "memory")
#define BAR()    __builtin_amdgcn_s_barrier()

// ---------------------------------------------------------------------------
// 256x256 BT GEMM, BK=64, 512 threads = 8 waves (2M x 4N), per-wave 128x64
// output spread across quadrant halves. C[a][b] = scale * sum A[a,i]*B[b,i].
// CMODE: 0 = bf16 + bias; 2 = bf16 exp(); 3 = bf16 at split-K z*zstride.
// LDS half [128 rows][8 granules of 8 shorts]: slot s of row r holds global
// granule s^(r&7); read granule ks*4+quad -> slot (ks*4+quad)^(l16&7).
// (0 bank conflicts, verified R7-R10.)  Requires K % 128 == 0.
// ---------------------------------------------------------------------------
template<int CMODE>
__global__ __launch_bounds__(512)
void gemm256(const short* __restrict__ A, int lda,
             const short* __restrict__ B, int ldb,
             const float* __restrict__ bias,
             short* __restrict__ Cout, int ldc, float scale,
             int K, size_t zstride)
{
    __shared__ __align__(16) short As[2][2][128 * 64];  // [parity][mq-half]
    __shared__ __align__(16) short Bs[2][2][128 * 64];  // [parity][nq-half]

    const int tid  = threadIdx.x;
    const int lane = tid & 63;
    const int wave = tid >> 6;           // 0..7
    const int wr   = wave >> 2;          // 0..1
    const int wc   = wave & 3;           // 0..3
    const int quad = lane >> 4;
    const int l16  = lane & 15;
    const size_t bm0 = (size_t)blockIdx.y * 256;
    const size_t bn0 = (size_t)blockIdx.x * 256;
    const int koff = blockIdx.z * K;

    f32x4 acc[8][4] = {};

    // staging decode: stage call writes 16 rows (wave*16..+15) of one half;
    // lane l -> row +8*i+(l>>3), LDS slot (l&7), global granule (l&7)^(l>>3)
    const int srow  = lane >> 3;
    const int sgran = (lane & 7) ^ srow;
    const short* Ag0 = A + (bm0 + wave * 16 + srow) * (size_t)lda + koff + sgran * 8;
    const short* Ag1 = Ag0 + (size_t)128 * lda;
    const short* Bg0 = B + (bn0 + wave * 16 + srow) * (size_t)ldb + koff + sgran * 8;
    const short* Bg1 = Bg0 + (size_t)128 * ldb;

    // fragment read offsets within a [128][64] half
    const int s0   = ((quad ^ (l16 & 7)) << 3);         // ks=0 slot
    const int s1   = (((4 + quad) ^ (l16 & 7)) << 3);   // ks=1 slot
    const int rdA0 = (wr * 64 + l16) * 64;
    const int rdB0 = (wc * 32 + l16) * 64;

    auto stage = [&](short* half, const short* g, int ld, int kt) {
#pragma unroll
        for (int i = 0; i < 2; ++i)
            gld_lds16(g + (size_t)(i * 8) * ld + kt,
                      half + (wave * 16 + i * 8) * 64);
    };

    bf16x8 af[4][2], bfr0[2][2], bfr1[2][2];

    auto ldAf = [&](const short* Ah) {
#pragma unroll
        for (int m4 = 0; m4 < 4; ++m4) {
            af[m4][0] = *(const bf16x8*)(Ah + rdA0 + m4 * 1024 + s0);
            af[m4][1] = *(const bf16x8*)(Ah + rdA0 + m4 * 1024 + s1);
        }
    };
    auto ldBf = [&](bf16x8 (&bx)[2][2], const short* Bh) {
#pragma unroll
        for (int n2 = 0; n2 < 2; ++n2) {
            bx[n2][0] = *(const bf16x8*)(Bh + rdB0 + n2 * 1024 + s0);
            bx[n2][1] = *(const bf16x8*)(Bh + rdB0 + n2 * 1024 + s1);
        }
    };
    auto mm = [&](int mq, int nq, bf16x8 (&bx)[2][2]) {
        __builtin_amdgcn_s_setprio(1);
#pragma unroll
        for (int ks = 0; ks < 2; ++ks)
#pragma unroll
            for (int m4 = 0; m4 < 4; ++m4)
#pragma unroll
                for (int n2 = 0; n2 < 2; ++n2)
                    acc[mq * 4 + m4][nq * 2 + n2] =
                        __builtin_amdgcn_mfma_f32_16x16x32_bf16(
                            af[m4][ks], bx[n2][ks],
                            acc[mq * 4 + m4][nq * 2 + n2], 0, 0, 0);
        __builtin_amdgcn_s_setprio(0);
    };

    // prologue: tile0 all 4 halves (8 loads, retired by vmcnt(6)), then
    // tile1 {A0,B0,B1} (6 loads, stay in flight). tile1.A1 staged at ph1.
    stage(&As[0][0][0], Ag0, lda, 0);
    stage(&Bs[0][0][0], Bg0, ldb, 0);
    stage(&Bs[0][1][0], Bg1, ldb, 0);
    stage(&As[0][1][0], Ag1, lda, 0);
    stage(&As[1][0][0], Ag0, lda, 64);
    stage(&Bs[1][0][0], Bg0, ldb, 64);
    stage(&Bs[1][1][0], Bg1, ldb, 64);
    WAITV(6);
    BAR();
    __builtin_amdgcn_sched_barrier(0);

    int kt = 0;
    auto iterbody = [&](auto LASTC) {
        constexpr bool LAST = decltype(LASTC)::value;
        // ---- ph1: tile t, quadrant (0,0) ----
        ldAf(&As[0][0][0]);
        ldBf(bfr0, &Bs[0][0][0]);
        stage(&As[1][1][0], Ag1, lda, kt + 64);        // t+1.A1
        LGKM8();
        BAR();
        LGKM0();
        mm(0, 0, bfr0);
        BAR();
        // ---- ph2: (0,1) ----
        ldBf(bfr1, &Bs[0][1][0]);
        if constexpr (!LAST) stage(&As[0][0][0], Ag0, lda, kt + 128);  // t+2.A0
        BAR();
        LGKM0();
        mm(0, 1, bfr1);
        BAR();
        // ---- ph3: (1,1) ----
        ldAf(&As[0][1][0]);
        if constexpr (!LAST) stage(&Bs[0][0][0], Bg0, ldb, kt + 128);  // t+2.B0
        BAR();
        LGKM0();
        mm(1, 1, bfr1);
        BAR();
        // ---- ph4: (1,0) — register-only MFMA, publish tile t+1 ----
        if constexpr (!LAST) stage(&Bs[0][1][0], Bg1, ldb, kt + 128);  // t+2.B1
        mm(1, 0, bfr0);
        if constexpr (LAST) { WAITV(0); } else { WAITV(6); }
        BAR();
        // ---- ph5: tile t+1, quadrant (0,0) ----
        ldAf(&As[1][0][0]);
        ldBf(bfr0, &Bs[1][0][0]);
        if constexpr (!LAST) stage(&As[0][1][0], Ag1, lda, kt + 128);  // t+2.A1
        LGKM8();
        BAR();
        LGKM0();
        mm(0, 0, bfr0);
        BAR();
        // ---- ph6: (0,1) ----
        ldBf(bfr1, &Bs[1][1][0]);
        if constexpr (!LAST) stage(&As[1][0][0], Ag0, lda, kt + 192);  // t+3.A0
        BAR();
        LGKM0();
        mm(0, 1, bfr1);
        BAR();
        // ---- ph7: (1,1) ----
        ldAf(&As[1][1][0]);
        if constexpr (!LAST) stage(&Bs[1][0][0], Bg0, ldb, kt + 192);  // t+3.B0
        BAR();
        LGKM0();
        mm(1, 1, bfr1);
        BAR();
        // ---- ph8: (1,0) — register-only MFMA, publish tile t+2 ----
        if constexpr (!LAST) stage(&Bs[1][1][0], Bg1, ldb, kt + 192);  // t+3.B1
        mm(1, 0, bfr0);
        if constexpr (!LAST) { WAITV(6); }
        BAR();
    };

    const int nfull = (K >> 7) - 1;      // K % 128 == 0
    for (int i = 0; i < nfull; ++i) {
        iterbody(FalseT{});
        kt += 128;
    }
    iterbody(TrueT{});

    // epilogue: C/D layout col=lane&15, row=quad*4+reg; wave rows/cols are
    // split across the two quadrant halves.
    short* Cs = Cout + ((CMODE == 3) ? (size_t)blockIdx.z * zstride : 0);
#pragma unroll
    for (int mt = 0; mt < 8; ++mt) {
        const int mq = mt >> 2, m4 = mt & 3;
#pragma unroll
        for (int nt = 0; nt < 4; ++nt) {
            const int nq = nt >> 1, n2 = nt & 1;
            const size_t col = bn0 + nq * 128 + wc * 32 + n2 * 16 + l16;
            const float bc = (CMODE == 0) ? bias[col] : 0.0f;
#pragma unroll
            for (int r = 0; r < 4; ++r) {
                const size_t row = bm0 + mq * 128 + wr * 64 + m4 * 16 + quad * 4 + r;
                float v = acc[mt][nt][r] * scale + bc;
                if (CMODE == 2) v = __expf(v);
                Cs[row * (size_t)ldc + col] = f2bf(v);
            }
        }
    }
}

// 64x64 LDS-tiled transpose: vt[d][n] = qkv[n*3072 + 2048 + d]
__global__ __launch_bounds__(256)
void transpose_v(const short* __restrict__ qkv, short* __restrict__ vt)
{
    __shared__ short sh[64][72];   // +8 pad
    const int n0 = blockIdx.x * 64, d0 = blockIdx.y * 64;
    const int t = threadIdx.x;
    const int r = t >> 2, c = (t & 3) << 4;

    const short* src = qkv + (size_t)(n0 + r) * 3072 + 2048 + d0 + c;
    *(int4*)(&sh[r][c])     = *(const int4*)(src);
    *(int4*)(&sh[r][c + 8]) = *(const int4*)(src + 8);
    __syncthreads();

    short tmp[16];
#pragma unroll
    for (int j = 0; j < 16; j++) tmp[j] = sh[c + j][r];
    short* dst = vt + (size_t)(d0 + r) * 4096 + n0 + c;
    *(int4*)(dst)     = *(const int4*)(tmp);
    *(int4*)(dst + 8) = *(const int4*)(tmp + 8);
}

// One block per output row n: rsum = sum(E[n,:]); out[n,:] =
// (sum_z partial_z[n,:]) / rsum. Partials are bf16, 4 splits of 4096x1024.
__global__ __launch_bounds__(256)
void reduce4div(const short* __restrict__ E, const short* __restrict__ outp,
                float* __restrict__ out)
{
    const int row = blockIdx.x;
    const int t = threadIdx.x;
    const int wave = t >> 6, lane = t & 63;

    // row-sum of E[row][4096], 16 elems/thread
    const short* e = E + (size_t)row * 4096 + (t << 4);
    short sh[16];
    *(int4*)(sh)     = *(const int4*)(e);
    *(int4*)(sh + 8) = *(const int4*)(e + 8);
    float s = 0.0f;
#pragma unroll
    for (int i = 0; i < 16; i++) s += bf2f(sh[i]);
#pragma unroll
    for (int off = 32; off; off >>= 1) s += __shfl_down(s, off);
    __shared__ float red[4];
    if (lane == 0) red[wave] = s;
    __syncthreads();
    const float inv = 1.0f / (red[0] + red[1] + red[2] + red[3]);

    // sum 4 bf16 partial rows, 4 cols/thread
    const size_t base = (size_t)row * 1024 + (t << 2);
    float a[4] = {0.0f, 0.0f, 0.0f, 0.0f};
#pragma unroll
    for (int z = 0; z < 4; z++) {
        short4 p = *(const short4*)(outp + z * (size_t)4096 * 1024 + base);
        a[0] += bf2f(p.x); a[1] += bf2f(p.y);
        a[2] += bf2f(p.z); a[3] += bf2f(p.w);
    }
    float4 o;
    o.x = a[0] * inv; o.y = a[1] * inv; o.z = a[2] * inv; o.w = a[3] * inv;
    *(float4*)(out + base) = o;
}

// single prep: x->xb (1M float4), W1|W2|W3 -> Wb (3x256K float4), bias cat
// Wb sub-matrix offsets are in SHORT ELEMENTS (1048576 elems per W).
__global__ __launch_bounds__(256)
void prep(const float* __restrict__ x, const float* __restrict__ W1,
          const float* __restrict__ W2, const float* __restrict__ W3,
          const float* __restrict__ b1, const float* __restrict__ b2,
          const float* __restrict__ b3,
          short* __restrict__ xb, short* __restrict__ Wb,
          float* __restrict__ bcat)
{
    const int i = blockIdx.x * 256 + threadIdx.x;
    const int NX = 1048576;           // 4096*1024/4
    const int NW = 262144;            // 1024*1024/4
    if (i < NX + 3 * NW) {
        const float* src; short* dst; int j;
        if (i < NX)               { src = x;  dst = xb; j = i; }
        else if (i < NX + NW)     { src = W1; dst = Wb; j = i - NX; }
        else if (i < NX + 2 * NW) { src = W2; dst = Wb + 1048576; j = i - NX - NW; }
        else                      { src = W3; dst = Wb + 2097152; j = i - NX - 2 * NW; }
        const float4 f = ((const float4*)src)[j];
        short4 o;
        o.x = f2bf(f.x); o.y = f2bf(f.y); o.z = f2bf(f.z); o.w = f2bf(f.w);
        *(short4*)(dst + (j << 2)) = o;
    } else {
        const int j = i - (NX + 3 * NW);
        if (j < 3072)
            bcat[j] = (j < 1024) ? b1[j] : (j < 2048 ? b2[j - 1024] : b3[j - 2048]);
    }
}

extern "C" void kernel_launch(void* const* d_in, const int* in_sizes, int n_in,
                              void* d_out, int out_size, void* d_ws, size_t ws_size,
                              hipStream_t stream)
{
    const float* x  = (const float*)d_in[0];
    const float* W1 = (const float*)d_in[1];
    const float* b1 = (const float*)d_in[2];
    const float* W2 = (const float*)d_in[3];
    const float* b2 = (const float*)d_in[4];
    const float* W3 = (const float*)d_in[5];
    const float* b3 = (const float*)d_in[6];
    float* out = (float*)d_out;

    const int N = 4096, D = 1024;

    // workspace (peak 79 MB):
    //   vt   [0, 8M)            live: transpose .. out-gemm
    //   E    [8M, 40M)          live: S-gemm .. reduce
    //   xb   [40M, 48M)  \
    //   Wb   [48M, 54M)   }     dead after S-gemm
    //   bcat [54M, +12K)  }
    //   qkv  [54M+16K, ~78M)   /
    //   outp [40M, 72M)         bf16 partials, overlays dead region
    char* wsb = (char*)d_ws;
    short* vt   = (short*)wsb;                               // 1024x4096 bf16
    short* E    = (short*)(wsb + (size_t)8  * 1024 * 1024);  // 4096x4096 bf16
    short* xb   = (short*)(wsb + (size_t)40 * 1024 * 1024);  // 4096x1024 bf16
    short* Wb   = (short*)(wsb + (size_t)48 * 1024 * 1024);  // 3072x1024 bf16
    float* bcat = (float*)(wsb + (size_t)54 * 1024 * 1024);  // 3072 fp32
    short* qkv  = (short*)(wsb + (size_t)54 * 1024 * 1024 + 16384); // 4096x3072
    short* outp = (short*)(wsb + (size_t)40 * 1024 * 1024);  // 4x 4096x1024 bf16

    // 1) prep: casts + bias concat (one launch)
    prep<<<(1048576 + 3 * 262144 + 3072 + 255) / 256, 256, 0, stream>>>(
        x, W1, W2, W3, b1, b2, b3, xb, Wb, bcat);

    // 2) qkv = x @ [W1;W2;W3]^T + bias  (256x256, grid (12,16)=192)
    dim3 gqkv(3 * D / 256, N / 256);
    gemm256<0><<<gqkv, 512, 0, stream>>>(xb, D, Wb, D, bcat,
                                         qkv, 3 * D, 1.0f, D, 0);

    // 3) vt[d][n] = v[n][d]   grid (64,16)=1024 blocks
    dim3 gt(N / 64, D / 64);
    transpose_v<<<gt, 256, 0, stream>>>(qkv, vt);

    // 4) E = exp((k q^T)/32) bf16  (256x256, grid (16,16)=256)
    dim3 gs(N / 256, N / 256);
    gemm256<2><<<gs, 512, 0, stream>>>(qkv + D, 3 * D, qkv, 3 * D,
                                       nullptr, E, N, 0.03125f, D, 0);

    // 5) out partials = E @ vt^T, split-K=4, bf16 (grid (4,16,4)=256)
    dim3 go(D / 256, N / 256, 4);
    gemm256<3><<<go, 512, 0, stream>>>(E, N, vt, N, nullptr,
                                       outp, D, 1.0f, N / 4,
                                       (size_t)N * D);

    // 6) out = (sum_z partial_z) / rowsum(E)
    reduce4div<<<N, 256, 0, stream>>>(E, outp, out);
}

// Round 5
// 212.500 us; speedup vs baseline: 1.1674x; 1.0257x over previous
//
#include <hip/hip_runtime.h>

// ---------------------------------------------------------------------------
// self_transformer: q=xW1^T+b1, k=xW2^T+b2, v=xW3^T+b3,
//                   attn=softmax((k q^T)/sqrt(D)), out=attn@v
// N=4096, D=1024. All matmuls via mfma_f32_16x16x32_bf16, fp32 accum.
// R12 = R11 minus the intra-phase serialization:
//   - REMOVED: per-phase lgkmcnt(0)+sched_barrier pins and the pre-MFMA
//     barrier. R11's pins forced the whole 8-wave LDS read burst (up to 96
//     b128 = ~1100 cyc of LDS-pipe time) to fully drain while ALL waves sat
//     at lgkmcnt(0), then ran 620 cyc of MFMA with LDS idle -> observed
//     1630 cyc/phase vs 620 floor (MfmaUtil stuck at 29%).
//   - NOW: reads issued in consume order (B-ks0, A-ks0, B-ks1, A-ks1);
//     compiler emits per-use counted lgkmcnt (verified m97 behavior), so
//     each wave's MFMA cluster starts after ~5 reads and the rest drain
//     UNDER the MFMAs; 1 barrier per phase (post-MFMA) re-syncs.
//   - KEPT from R11 (unchanged ledger):
//     stage rotation ph1:t+1.A1, ph2:t+2.A0, ph3:t+2.B0, ph4:t+2.B1,
//     ph5:t+2.A1, ph6:t+3.A0, ph7:t+3.B0, ph8:t+3.B1; vmcnt(6) publishes
//     at end-ph4 (tile t+1 complete) / end-ph8 (tile t+2 complete), with
//     sched_barrier(0) so no memory op crosses; last iteration peeled
//     (vmcnt(0) only there).
//   WAR safety: every stage targets a slot whose reads completed in an
//   earlier phase (reads complete before that wave's last MFMA -> before
//   that phase's barrier; stage issues after it). RAW safety: phase-p
//   reads are issued after the publish wait+barrier covering their slot.
//   Per-element accumulation order (tile-major, ks0->ks1) unchanged ->
//   bit-identical numerics to R11.
// ---------------------------------------------------------------------------

typedef short bf16x8 __attribute__((ext_vector_type(8)));  // 8 bf16 = 4 VGPRs
typedef float f32x4  __attribute__((ext_vector_type(4)));

struct FalseT { static constexpr bool value = false; };
struct TrueT  { static constexpr bool value = true;  };

__device__ __forceinline__ short f2bf(float f) {
    unsigned u = __builtin_bit_cast(unsigned, f);
    u += 0x7FFFu + ((u >> 16) & 1u);   // round-to-nearest-even
    return (short)(u >> 16);
}
__device__ __forceinline__ float bf2f(short s) {
    return __builtin_bit_cast(float, (unsigned)((unsigned short)s) << 16);
}

__device__ __forceinline__ void gld_lds16(const short* g, short* l) {
    __builtin_amdgcn_global_load_lds(
        (const __attribute__((address_space(1))) void*)g,
        (__attribute__((address_space(3))) void*)l, 16, 0, 0);
}

#define WAITV(n) asm volatile("s_waitcnt vmcnt(" #n ")" ::: "memory")
#define BAR()    __builtin_amdgcn_s_barrier()

// ---------------------------------------------------------------------------
// 256x256 BT GEMM, BK=64, 512 threads = 8 waves (2M x 4N), per-wave 128x64
// output spread across quadrant halves. C[a][b] = scale * sum A[a,i]*B[b,i].
// CMODE: 0 = bf16 + bias; 2 = bf16 exp(); 3 = bf16 at split-K z*zstride.
// LDS half [128 rows][8 granules of 8 shorts]: slot s of row r holds global
// granule s^(r&7); read granule ks*4+quad -> slot (ks*4+quad)^(l16&7).
// (0 bank conflicts, verified R7-R11.)  Requires K % 128 == 0.
// ---------------------------------------------------------------------------
template<int CMODE>
__global__ __launch_bounds__(512)
void gemm256(const short* __restrict__ A, int lda,
             const short* __restrict__ B, int ldb,
             const float* __restrict__ bias,
             short* __restrict__ Cout, int ldc, float scale,
             int K, size_t zstride)
{
    __shared__ __align__(16) short As[2][2][128 * 64];  // [parity][mq-half]
    __shared__ __align__(16) short Bs[2][2][128 * 64];  // [parity][nq-half]

    const int tid  = threadIdx.x;
    const int lane = tid & 63;
    const int wave = tid >> 6;           // 0..7
    const int wr   = wave >> 2;          // 0..1
    const int wc   = wave & 3;           // 0..3
    const int quad = lane >> 4;
    const int l16  = lane & 15;
    const size_t bm0 = (size_t)blockIdx.y * 256;
    const size_t bn0 = (size_t)blockIdx.x * 256;
    const int koff = blockIdx.z * K;

    f32x4 acc[8][4] = {};

    // staging decode: stage call writes 16 rows (wave*16..+15) of one half;
    // lane l -> row +8*i+(l>>3), LDS slot (l&7), global granule (l&7)^(l>>3)
    const int srow  = lane >> 3;
    const int sgran = (lane & 7) ^ srow;
    const short* Ag0 = A + (bm0 + wave * 16 + srow) * (size_t)lda + koff + sgran * 8;
    const short* Ag1 = Ag0 + (size_t)128 * lda;
    const short* Bg0 = B + (bn0 + wave * 16 + srow) * (size_t)ldb + koff + sgran * 8;
    const short* Bg1 = Bg0 + (size_t)128 * ldb;

    // fragment read offsets within a [128][64] half
    const int s0   = ((quad ^ (l16 & 7)) << 3);         // ks=0 slot
    const int s1   = (((4 + quad) ^ (l16 & 7)) << 3);   // ks=1 slot
    const int rdA0 = (wr * 64 + l16) * 64;
    const int rdB0 = (wc * 32 + l16) * 64;

    auto stage = [&](short* half, const short* g, int ld, int kt) {
#pragma unroll
        for (int i = 0; i < 2; ++i)
            gld_lds16(g + (size_t)(i * 8) * ld + kt,
                      half + (wave * 16 + i * 8) * 64);
    };

    bf16x8 af[4][2], bfr0[2][2], bfr1[2][2];

    auto ldA = [&](const short* Ah, int ks, int soff) {
#pragma unroll
        for (int m4 = 0; m4 < 4; ++m4)
            af[m4][ks] = *(const bf16x8*)(Ah + rdA0 + m4 * 1024 + soff);
    };
    auto ldB = [&](bf16x8 (&bx)[2][2], const short* Bh, int ks, int soff) {
#pragma unroll
        for (int n2 = 0; n2 < 2; ++n2)
            bx[n2][ks] = *(const bf16x8*)(Bh + rdB0 + n2 * 1024 + soff);
    };
    auto mmks = [&](int mq, int nq, bf16x8 (&bx)[2][2], int ks) {
#pragma unroll
        for (int m4 = 0; m4 < 4; ++m4)
#pragma unroll
            for (int n2 = 0; n2 < 2; ++n2)
                acc[mq * 4 + m4][nq * 2 + n2] =
                    __builtin_amdgcn_mfma_f32_16x16x32_bf16(
                        af[m4][ks], bx[n2][ks],
                        acc[mq * 4 + m4][nq * 2 + n2], 0, 0, 0);
    };

    // prologue: tile0 all 4 halves (8 loads, retired by vmcnt(6)), then
    // tile1 {A0,B0,B1} (6 loads, stay in flight). tile1.A1 staged at ph1.
    stage(&As[0][0][0], Ag0, lda, 0);
    stage(&Bs[0][0][0], Bg0, ldb, 0);
    stage(&Bs[0][1][0], Bg1, ldb, 0);
    stage(&As[0][1][0], Ag1, lda, 0);
    stage(&As[1][0][0], Ag0, lda, 64);
    stage(&Bs[1][0][0], Bg0, ldb, 64);
    stage(&Bs[1][1][0], Bg1, ldb, 64);
    WAITV(6);
    BAR();
    __builtin_amdgcn_sched_barrier(0);

    int kt = 0;
    auto iterbody = [&](auto LASTC) {
        constexpr bool LAST = decltype(LASTC)::value;
        // ---- ph1: tile t, quadrant (0,0) ----
        ldB(bfr0, &Bs[0][0][0], 0, s0);
        ldA(&As[0][0][0], 0, s0);
        ldB(bfr0, &Bs[0][0][0], 1, s1);
        ldA(&As[0][0][0], 1, s1);
        stage(&As[1][1][0], Ag1, lda, kt + 64);        // t+1.A1
        __builtin_amdgcn_s_setprio(1);
        mmks(0, 0, bfr0, 0); mmks(0, 0, bfr0, 1);
        __builtin_amdgcn_s_setprio(0);
        BAR();
        // ---- ph2: (0,1) ----
        ldB(bfr1, &Bs[0][1][0], 0, s0);
        ldB(bfr1, &Bs[0][1][0], 1, s1);
        if constexpr (!LAST) stage(&As[0][0][0], Ag0, lda, kt + 128);  // t+2.A0
        __builtin_amdgcn_s_setprio(1);
        mmks(0, 1, bfr1, 0); mmks(0, 1, bfr1, 1);
        __builtin_amdgcn_s_setprio(0);
        BAR();
        // ---- ph3: (1,1) ----
        ldA(&As[0][1][0], 0, s0);
        ldA(&As[0][1][0], 1, s1);
        if constexpr (!LAST) stage(&Bs[0][0][0], Bg0, ldb, kt + 128);  // t+2.B0
        __builtin_amdgcn_s_setprio(1);
        mmks(1, 1, bfr1, 0); mmks(1, 1, bfr1, 1);
        __builtin_amdgcn_s_setprio(0);
        BAR();
        // ---- ph4: (1,0) — register-only MFMA, publish tile t+1 ----
        if constexpr (!LAST) stage(&Bs[0][1][0], Bg1, ldb, kt + 128);  // t+2.B1
        __builtin_amdgcn_s_setprio(1);
        mmks(1, 0, bfr0, 0); mmks(1, 0, bfr0, 1);
        __builtin_amdgcn_s_setprio(0);
        if constexpr (LAST) { WAITV(0); } else { WAITV(6); }
        __builtin_amdgcn_sched_barrier(0);
        BAR();
        // ---- ph5: tile t+1, quadrant (0,0) ----
        ldB(bfr0, &Bs[1][0][0], 0, s0);
        ldA(&As[1][0][0], 0, s0);
        ldB(bfr0, &Bs[1][0][0], 1, s1);
        ldA(&As[1][0][0], 1, s1);
        if constexpr (!LAST) stage(&As[0][1][0], Ag1, lda, kt + 128);  // t+2.A1
        __builtin_amdgcn_s_setprio(1);
        mmks(0, 0, bfr0, 0); mmks(0, 0, bfr0, 1);
        __builtin_amdgcn_s_setprio(0);
        BAR();
        // ---- ph6: (0,1) ----
        ldB(bfr1, &Bs[1][1][0], 0, s0);
        ldB(bfr1, &Bs[1][1][0], 1, s1);
        if constexpr (!LAST) stage(&As[1][0][0], Ag0, lda, kt + 192);  // t+3.A0
        __builtin_amdgcn_s_setprio(1);
        mmks(0, 1, bfr1, 0); mmks(0, 1, bfr1, 1);
        __builtin_amdgcn_s_setprio(0);
        BAR();
        // ---- ph7: (1,1) ----
        ldA(&As[1][1][0], 0, s0);
        ldA(&As[1][1][0], 1, s1);
        if constexpr (!LAST) stage(&Bs[1][0][0], Bg0, ldb, kt + 192);  // t+3.B0
        __builtin_amdgcn_s_setprio(1);
        mmks(1, 1, bfr1, 0); mmks(1, 1, bfr1, 1);
        __builtin_amdgcn_s_setprio(0);
        BAR();
        // ---- ph8: (1,0) — register-only MFMA, publish tile t+2 ----
        if constexpr (!LAST) stage(&Bs[1][1][0], Bg1, ldb, kt + 192);  // t+3.B1
        __builtin_amdgcn_s_setprio(1);
        mmks(1, 0, bfr0, 0); mmks(1, 0, bfr0, 1);
        __builtin_amdgcn_s_setprio(0);
        if constexpr (!LAST) {
            WAITV(6);
            __builtin_amdgcn_sched_barrier(0);
        }
        BAR();
    };

    const int nfull = (K >> 7) - 1;      // K % 128 == 0
    for (int i = 0; i < nfull; ++i) {
        iterbody(FalseT{});
        kt += 128;
    }
    iterbody(TrueT{});

    // epilogue: C/D layout col=lane&15, row=quad*4+reg; wave rows/cols are
    // split across the two quadrant halves.
    short* Cs = Cout + ((CMODE == 3) ? (size_t)blockIdx.z * zstride : 0);
#pragma unroll
    for (int mt = 0; mt < 8; ++mt) {
        const int mq = mt >> 2, m4 = mt & 3;
#pragma unroll
        for (int nt = 0; nt < 4; ++nt) {
            const int nq = nt >> 1, n2 = nt & 1;
            const size_t col = bn0 + nq * 128 + wc * 32 + n2 * 16 + l16;
            const float bc = (CMODE == 0) ? bias[col] : 0.0f;
#pragma unroll
            for (int r = 0; r < 4; ++r) {
                const size_t row = bm0 + mq * 128 + wr * 64 + m4 * 16 + quad * 4 + r;
                float v = acc[mt][nt][r] * scale + bc;
                if (CMODE == 2) v = __expf(v);
                Cs[row * (size_t)ldc + col] = f2bf(v);
            }
        }
    }
}

// 64x64 LDS-tiled transpose: vt[d][n] = qkv[n*3072 + 2048 + d]
__global__ __launch_bounds__(256)
void transpose_v(const short* __restrict__ qkv, short* __restrict__ vt)
{
    __shared__ short sh[64][72];   // +8 pad
    const int n0 = blockIdx.x * 64, d0 = blockIdx.y * 64;
    const int t = threadIdx.x;
    const int r = t >> 2, c = (t & 3) << 4;

    const short* src = qkv + (size_t)(n0 + r) * 3072 + 2048 + d0 + c;
    *(int4*)(&sh[r][c])     = *(const int4*)(src);
    *(int4*)(&sh[r][c + 8]) = *(const int4*)(src + 8);
    __syncthreads();

    short tmp[16];
#pragma unroll
    for (int j = 0; j < 16; j++) tmp[j] = sh[c + j][r];
    short* dst = vt + (size_t)(d0 + r) * 4096 + n0 + c;
    *(int4*)(dst)     = *(const int4*)(tmp);
    *(int4*)(dst + 8) = *(const int4*)(tmp + 8);
}

// One block per output row n: rsum = sum(E[n,:]); out[n,:] =
// (sum_z partial_z[n,:]) / rsum. Partials are bf16, 4 splits of 4096x1024.
__global__ __launch_bounds__(256)
void reduce4div(const short* __restrict__ E, const short* __restrict__ outp,
                float* __restrict__ out)
{
    const int row = blockIdx.x;
    const int t = threadIdx.x;
    const int wave = t >> 6, lane = t & 63;

    // row-sum of E[row][4096], 16 elems/thread
    const short* e = E + (size_t)row * 4096 + (t << 4);
    short sh[16];
    *(int4*)(sh)     = *(const int4*)(e);
    *(int4*)(sh + 8) = *(const int4*)(e + 8);
    float s = 0.0f;
#pragma unroll
    for (int i = 0; i < 16; i++) s += bf2f(sh[i]);
#pragma unroll
    for (int off = 32; off; off >>= 1) s += __shfl_down(s, off);
    __shared__ float red[4];
    if (lane == 0) red[wave] = s;
    __syncthreads();
    const float inv = 1.0f / (red[0] + red[1] + red[2] + red[3]);

    // sum 4 bf16 partial rows, 4 cols/thread
    const size_t base = (size_t)row * 1024 + (t << 2);
    float a[4] = {0.0f, 0.0f, 0.0f, 0.0f};
#pragma unroll
    for (int z = 0; z < 4; z++) {
        short4 p = *(const short4*)(outp + z * (size_t)4096 * 1024 + base);
        a[0] += bf2f(p.x); a[1] += bf2f(p.y);
        a[2] += bf2f(p.z); a[3] += bf2f(p.w);
    }
    float4 o;
    o.x = a[0] * inv; o.y = a[1] * inv; o.z = a[2] * inv; o.w = a[3] * inv;
    *(float4*)(out + base) = o;
}

// single prep: x->xb (1M float4), W1|W2|W3 -> Wb (3x256K float4), bias cat
// Wb sub-matrix offsets are in SHORT ELEMENTS (1048576 elems per W).
__global__ __launch_bounds__(256)
void prep(const float* __restrict__ x, const float* __restrict__ W1,
          const float* __restrict__ W2, const float* __restrict__ W3,
          const float* __restrict__ b1, const float* __restrict__ b2,
          const float* __restrict__ b3,
          short* __restrict__ xb, short* __restrict__ Wb,
          float* __restrict__ bcat)
{
    const int i = blockIdx.x * 256 + threadIdx.x;
    const int NX = 1048576;           // 4096*1024/4
    const int NW = 262144;            // 1024*1024/4
    if (i < NX + 3 * NW) {
        const float* src; short* dst; int j;
        if (i < NX)               { src = x;  dst = xb; j = i; }
        else if (i < NX + NW)     { src = W1; dst = Wb; j = i - NX; }
        else if (i < NX + 2 * NW) { src = W2; dst = Wb + 1048576; j = i - NX - NW; }
        else                      { src = W3; dst = Wb + 2097152; j = i - NX - 2 * NW; }
        const float4 f = ((const float4*)src)[j];
        short4 o;
        o.x = f2bf(f.x); o.y = f2bf(f.y); o.z = f2bf(f.z); o.w = f2bf(f.w);
        *(short4*)(dst + (j << 2)) = o;
    } else {
        const int j = i - (NX + 3 * NW);
        if (j < 3072)
            bcat[j] = (j < 1024) ? b1[j] : (j < 2048 ? b2[j - 1024] : b3[j - 2048]);
    }
}

extern "C" void kernel_launch(void* const* d_in, const int* in_sizes, int n_in,
                              void* d_out, int out_size, void* d_ws, size_t ws_size,
                              hipStream_t stream)
{
    const float* x  = (const float*)d_in[0];
    const float* W1 = (const float*)d_in[1];
    const float* b1 = (const float*)d_in[2];
    const float* W2 = (const float*)d_in[3];
    const float* b2 = (const float*)d_in[4];
    const float* W3 = (const float*)d_in[5];
    const float* b3 = (const float*)d_in[6];
    float* out = (float*)d_out;

    const int N = 4096, D = 1024;

    // workspace (peak 79 MB):
    //   vt   [0, 8M)            live: transpose .. out-gemm
    //   E    [8M, 40M)          live: S-gemm .. reduce
    //   xb   [40M, 48M)  \
    //   Wb   [48M, 54M)   }     dead after S-gemm
    //   bcat [54M, +12K)  }
    //   qkv  [54M+16K, ~78M)   /
    //   outp [40M, 72M)         bf16 partials, overlays dead region
    char* wsb = (char*)d_ws;
    short* vt   = (short*)wsb;                               // 1024x4096 bf16
    short* E    = (short*)(wsb + (size_t)8  * 1024 * 1024);  // 4096x4096 bf16
    short* xb   = (short*)(wsb + (size_t)40 * 1024 * 1024);  // 4096x1024 bf16
    short* Wb   = (short*)(wsb + (size_t)48 * 1024 * 1024);  // 3072x1024 bf16
    float* bcat = (float*)(wsb + (size_t)54 * 1024 * 1024);  // 3072 fp32
    short* qkv  = (short*)(wsb + (size_t)54 * 1024 * 1024 + 16384); // 4096x3072
    short* outp = (short*)(wsb + (size_t)40 * 1024 * 1024);  // 4x 4096x1024 bf16

    // 1) prep: casts + bias concat (one launch)
    prep<<<(1048576 + 3 * 262144 + 3072 + 255) / 256, 256, 0, stream>>>(
        x, W1, W2, W3, b1, b2, b3, xb, Wb, bcat);

    // 2) qkv = x @ [W1;W2;W3]^T + bias  (256x256, grid (12,16)=192)
    dim3 gqkv(3 * D / 256, N / 256);
    gemm256<0><<<gqkv, 512, 0, stream>>>(xb, D, Wb, D, bcat,
                                         qkv, 3 * D, 1.0f, D, 0);

    // 3) vt[d][n] = v[n][d]   grid (64,16)=1024 blocks
    dim3 gt(N / 64, D / 64);
    transpose_v<<<gt, 256, 0, stream>>>(qkv, vt);

    // 4) E = exp((k q^T)/32) bf16  (256x256, grid (16,16)=256)
    dim3 gs(N / 256, N / 256);
    gemm256<2><<<gs, 512, 0, stream>>>(qkv + D, 3 * D, qkv, 3 * D,
                                       nullptr, E, N, 0.03125f, D, 0);

    // 5) out partials = E @ vt^T, split-K=4, bf16 (grid (4,16,4)=256)
    dim3 go(D / 256, N / 256, 4);
    gemm256<3><<<go, 512, 0, stream>>>(E, N, vt, N, nullptr,
                                       outp, D, 1.0f, N / 4,
                                       (size_t)N * D);

    // 6) out = (sum_z partial_z) / rowsum(E)
    reduce4div<<<N, 256, 0, stream>>>(E, outp, out);
}